// Round 11
// baseline (1810.150 us; speedup 1.0000x reference)
//
#include <hip/hip_runtime.h>

#define N_USERS 1000000
#define NEDGE   32000000
#define OUT_F   64
#define BN_EPS  1e-5f

// 2D binning geometry: key = (dst_bucket[0..245), src_quarter[0..4)).
// dst_bucket = dst>>12 (S_BUCKET=4096 nodes, dst_local packs in 12 bits);
// src_quarter: BALANCED split at 250k/500k/750k (round-10 bug: src>>18 gave
// quarters of 262144 nodes -> heavy-bin mean 34360 vs CAP 34832 = 2.6 sigma
// -> bin overflow -> corruption). Balanced: mean 32768, sigma ~181, 11.4 sigma
// slack. During hop sub-pass k all gathers fall in a ~1MB window of cur[] ->
// L2-resident (round-9: un-windowed gathers miss L2, 2.05GB/hop = 310us bound).
#define SBITS     12
#define S_BUCKET  4096
#define NB        245                     // ceil(N_USERS / S_BUCKET)
#define KSRC      4                       // src quarters
#define QW        250000                  // quarter width (balanced)
#define NBINS     (NB * KSRC)             // 980
#define CAP_BIN   34832                   // mean 32768 + 11.4 sigma, mult of 4
#define SCAT_BLOCKS 1024
#define TILE      4096                    // edges per scatter tile (LDS-sorted)
#define NTILES    ((NEDGE + TILE - 1) / TILE)
#define SPLIT     8                       // blocks per dst-bucket in the hop

typedef unsigned int uint4v __attribute__((ext_vector_type(4)));  // nontemporal-loadable

__device__ __forceinline__ int src_quarter(unsigned s) {
    return (s >= 1u * QW) + (s >= 2u * QW) + (s >= 3u * QW);
}

// ---------------- binned path ----------------

__global__ void init_cursors(unsigned* __restrict__ cursors) {
    int i = blockIdx.x * blockDim.x + threadIdx.x;
    if (i < NBINS) cursors[i] = (unsigned)i * CAP_BIN;
}

// Tile-sorted scatter into 980 (dst_bucket, src_quarter) bins: counting-sort
// the 4096-edge tile in LDS, reserve one contiguous global range per
// (tile,bin), flush coalesced runs. Meta = dst_local<<20 | src (unchanged).
__global__ __launch_bounds__(256) void scatter_bin(
    const int* __restrict__ src, const int* __restrict__ dst,
    const float* __restrict__ ew, uint2* __restrict__ rec,
    unsigned* __restrict__ cursors) {
    __shared__ uint2 srec[TILE];             // 32KB tile records, bin-sorted
    __shared__ unsigned short sbkt[TILE];    // 8KB bin id per sorted pos
    __shared__ unsigned hist[NBINS];         // counts -> exclusive seg starts
    __shared__ unsigned curs[NBINS];         // per-bin scatter cursor
    __shared__ unsigned gpos[NBINS];         // absolute global base of segment
    __shared__ unsigned chunkT[256];
    int tid = threadIdx.x;

    for (int tile = blockIdx.x; tile < NTILES; tile += gridDim.x) {
        int e0 = tile * TILE;
        int n_this = (e0 + TILE <= NEDGE) ? TILE : (NEDGE - e0);

        for (int i = tid; i < NBINS; i += 256) hist[i] = 0;
        __syncthreads();

        int dv[16], sv[16];
        #pragma unroll
        for (int k = 0; k < 16; ++k) {
            int e = e0 + k * 256 + tid;
            if (e < NEDGE) {
                dv[k] = __builtin_nontemporal_load(&dst[e]);
                sv[k] = __builtin_nontemporal_load(&src[e]);
                int bin = ((dv[k] >> SBITS) << 2) | src_quarter((unsigned)sv[k]);
                atomicAdd(&hist[bin], 1u);
            }
        }
        __syncthreads();

        // parallel exclusive scan over hist[980]: 4 bins/thread + chunk scan
        {
            int base = tid * 4;
            unsigned run = 0;
            #pragma unroll
            for (int k = 0; k < 4; ++k) {
                int idx = base + k;
                unsigned v = (idx < NBINS) ? hist[idx] : 0u;
                if (idx < NBINS) hist[idx] = run;
                run += v;
            }
            chunkT[tid] = run;
        }
        __syncthreads();
        if (tid == 0) {
            unsigned r = 0;
            for (int t = 0; t < 256; ++t) { unsigned v = chunkT[t]; chunkT[t] = r; r += v; }
        }
        __syncthreads();
        {
            int base = tid * 4;
            unsigned add = chunkT[tid];
            #pragma unroll
            for (int k = 0; k < 4; ++k) {
                int idx = base + k;
                if (idx < NBINS) hist[idx] += add;
            }
        }
        __syncthreads();

        for (int bn = tid; bn < NBINS; bn += 256) {
            unsigned st = hist[bn];
            unsigned en = (bn == NBINS - 1) ? (unsigned)n_this : hist[bn + 1];
            unsigned c = en - st;
            gpos[bn] = c ? atomicAdd(&cursors[bn], c) : 0u;
            curs[bn] = 0;
        }
        __syncthreads();

        #pragma unroll
        for (int k = 0; k < 16; ++k) {
            int e = e0 + k * 256 + tid;
            if (e < NEDGE) {
                int dd = dv[k], ss = sv[k];
                int bin = ((dd >> SBITS) << 2) | src_quarter((unsigned)ss);
                float w = __builtin_nontemporal_load(&ew[e]);
                unsigned p = hist[bin] + atomicAdd(&curs[bin], 1u);
                srec[p] = make_uint2(((unsigned)(dd & (S_BUCKET - 1)) << 20) | (unsigned)ss,
                                     __float_as_uint(w));
                sbkt[p] = (unsigned short)bin;
            }
        }
        __syncthreads();

        for (int i = tid; i < n_this; i += 256) {   // coalesced segment flush
            unsigned bn = sbkt[i];
            rec[gpos[bn] + ((unsigned)i - hist[bn])] = srec[i];
        }
        __syncthreads();                            // before next tile reuses LDS
    }
}

// LDS-accumulation hop with src-windowed gathers: SPLIT blocks per dst-bucket;
// each walks the bucket's 4 src-quarter sub-bins IN ORDER, so all concurrent
// gathers target a ~1MB L2-resident window of cur. ds_add_f32 accumulation
// (fire-and-forget), coalesced global atomicAdd flush (nxt pre-zeroed).
__global__ __launch_bounds__(256) void hop_bucket(
    const uint2* __restrict__ rec, const unsigned* __restrict__ cursors,
    const float* __restrict__ cur, float* __restrict__ nxt) {
    __shared__ float acc[S_BUCKET];
    int tid = threadIdx.x;
    int b = blockIdx.x / SPLIT;
    int sidx = blockIdx.x % SPLIT;
    for (int i = tid; i < S_BUCKET; i += 256) acc[i] = 0.0f;
    __syncthreads();

    for (int k = 0; k < KSRC; ++k) {
        int bin = b * KSRC + k;
        unsigned start = (unsigned)bin * CAP_BIN;    // mult of 4 -> 32B aligned
        unsigned cnt = cursors[bin] - start;
        unsigned u0 = ((cnt * (unsigned)sidx) / SPLIT) & ~3u;
        unsigned u1 = (sidx == SPLIT - 1) ? cnt : (((cnt * (unsigned)(sidx + 1)) / SPLIT) & ~3u);
        const uint2* bp = rec + start;

        unsigned i = u0 + 4u * (unsigned)tid;
        for (; i + 4u <= u1; i += 4u * 256u) {
            uint4v r0 = __builtin_nontemporal_load(reinterpret_cast<const uint4v*>(bp + i));
            uint4v r1 = __builtin_nontemporal_load(reinterpret_cast<const uint4v*>(bp + i + 2));
            float c0 = cur[r0.x & 0xFFFFFu];
            float c1 = cur[r0.z & 0xFFFFFu];
            float c2 = cur[r1.x & 0xFFFFFu];
            float c3 = cur[r1.z & 0xFFFFFu];
            atomicAdd(&acc[r0.x >> 20], c0 * __uint_as_float(r0.y));
            atomicAdd(&acc[r0.z >> 20], c1 * __uint_as_float(r0.w));
            atomicAdd(&acc[r1.x >> 20], c2 * __uint_as_float(r1.y));
            atomicAdd(&acc[r1.z >> 20], c3 * __uint_as_float(r1.w));
        }
        if (i < u1) {                                // at most one straddling quad
            for (unsigned j = i; j < i + 4u && j < u1; ++j) {
                uint2 r = bp[j];
                atomicAdd(&acc[r.x >> 20], cur[r.x & 0xFFFFFu] * __uint_as_float(r.y));
            }
        }
    }
    __syncthreads();

    int nb0 = b << SBITS;
    for (int k = tid; k < S_BUCKET; k += 256) {
        int n = nb0 + k;
        if (n < N_USERS) atomicAdd(&nxt[n], acc[k]);
    }
}

// ---------------- fallback path (device atomics, small workspace) ----------------

__global__ void zero_kernel(float* __restrict__ p, int n) {
    int i = blockIdx.x * blockDim.x + threadIdx.x;
    int stride = gridDim.x * blockDim.x;
    for (; i < n; i += stride) p[i] = 0.0f;
}

__global__ __launch_bounds__(256) void hop_atomic(
    const int* __restrict__ src, const int* __restrict__ dst,
    const float* __restrict__ ew, const float* __restrict__ cur,
    float* __restrict__ nxt) {
    int e = blockIdx.x * blockDim.x + threadIdx.x;
    if (e * 4 < NEDGE) {
        int4   s = ((const int4*)src)[e];
        int4   d = ((const int4*)dst)[e];
        float4 w = ((const float4*)ew)[e];
        atomicAdd(&nxt[d.x], cur[s.x] * w.x);
        atomicAdd(&nxt[d.y], cur[s.y] * w.y);
        atomicAdd(&nxt[d.z], cur[s.z] * w.z);
        atomicAdd(&nxt[d.w], cur[s.w] * w.w);
    }
}

// ---------------- finalize: 5->64 matvec + BatchNorm over features ----------------

__global__ __launch_bounds__(256) void finalize_kernel(
    const float* __restrict__ x,  const float* __restrict__ f1,
    const float* __restrict__ f2, const float* __restrict__ f3,
    const float* __restrict__ f4, const float* __restrict__ W,
    const float* __restrict__ bias, const float* __restrict__ gamma,
    const float* __restrict__ beta, float* __restrict__ out) {
    int lane = threadIdx.x & 63;
    int waveInBlock = threadIdx.x >> 6;
    int wavesPerBlock = blockDim.x >> 6;
    int gwave  = blockIdx.x * wavesPerBlock + waveInBlock;
    int nwaves = gridDim.x * wavesPerBlock;

    float w0 = W[lane * 5 + 0];
    float w1 = W[lane * 5 + 1];
    float w2 = W[lane * 5 + 2];
    float w3 = W[lane * 5 + 3];
    float w4 = W[lane * 5 + 4];
    float b  = bias[lane];

    for (int n = gwave; n < N_USERS; n += nwaves) {
        float c0 = x[n], c1 = f1[n], c2 = f2[n], c3 = f3[n], c4 = f4[n];
        float y = b + c0 * w0 + c1 * w1 + c2 * w2 + c3 * w3 + c4 * w4;

        float s = y;
        #pragma unroll
        for (int off = 32; off; off >>= 1) s += __shfl_xor(s, off);
        float mean = s * (1.0f / 64.0f);

        float d = y - mean;
        float v = d * d;
        #pragma unroll
        for (int off = 32; off; off >>= 1) v += __shfl_xor(v, off);
        float var = v * (1.0f / 64.0f);

        float o = d * rsqrtf(var + BN_EPS) * gamma[n] + beta[n];
        __builtin_nontemporal_store(o, &out[(size_t)n * OUT_F + lane]);
    }
}

extern "C" void kernel_launch(void* const* d_in, const int* in_sizes, int n_in,
                              void* d_out, int out_size, void* d_ws, size_t ws_size,
                              hipStream_t stream) {
    const float* x     = (const float*)d_in[0];
    const int*   ei    = (const int*)d_in[1];
    const float* ew    = (const float*)d_in[2];
    const float* W     = (const float*)d_in[3];
    const float* bias  = (const float*)d_in[4];
    const float* gamma = (const float*)d_in[5];
    const float* beta  = (const float*)d_in[6];
    float* out = (float*)d_out;

    const int* src = ei;
    const int* dst = ei + NEDGE;

    // Workspace layout (total ~289.1MB; known-available >= 304MB from rounds 0-1)
    float* f = (float*)d_ws;                                      // 16MB
    uint2* rec = (uint2*)(f + 4ull * N_USERS);                    // 273.1MB (padded bins)
    unsigned* cursors = (unsigned*)(rec + (size_t)NBINS * CAP_BIN);  // ~4KB
    size_t needed = 16000000ull + (size_t)NBINS * CAP_BIN * 8 + 4096;

    if (ws_size >= needed) {
        init_cursors<<<(NBINS + 255) / 256, 256, 0, stream>>>(cursors);
        zero_kernel<<<2048, 256, 0, stream>>>(f, 4 * N_USERS);   // hop flush is atomicAdd
        scatter_bin<<<SCAT_BLOCKS, 256, 0, stream>>>(src, dst, ew, rec, cursors);
        const float* cur = x;
        for (int h = 0; h < 4; ++h) {
            float* nxt = f + (size_t)h * N_USERS;
            hop_bucket<<<NB * SPLIT, 256, 0, stream>>>(rec, cursors, cur, nxt);
            cur = nxt;
        }
    } else {
        zero_kernel<<<4096, 256, 0, stream>>>(f, 4 * N_USERS);
        const float* cur = x;
        for (int h = 0; h < 4; ++h) {
            float* nxt = f + (size_t)h * N_USERS;
            hop_atomic<<<NEDGE / 4 / 256, 256, 0, stream>>>(src, dst, ew, cur, nxt);
            cur = nxt;
        }
    }

    finalize_kernel<<<2048, 256, 0, stream>>>(
        x, f, f + N_USERS, f + 2 * N_USERS, f + 3 * N_USERS,
        W, bias, gamma, beta, out);
}

// Round 12
// 1619.066 us; speedup vs baseline: 1.1180x; 1.1180x over previous
//
#include <hip/hip_runtime.h>

#define N_USERS 1000000
#define NEDGE   32000000
#define OUT_F   64
#define BN_EPS  1e-5f

// Destination binning geometry (1D, reverted from round-10/11 2D: src-windowing
// did not move hop time -> gather locality is not the hop bound).
// S_BUCKET=4096 is the max where meta packs: dst_local(12b)<<20 | src(20b).
#define SBITS     12
#define S_BUCKET  4096
#define NB        245                     // ceil(N_USERS / S_BUCKET)
#define CAP       136896                  // mean 130612 + ~17 sigma, mult of 8
#define SCAT_BLOCKS 1024
#define TILE      4096                    // edges per scatter tile (LDS-sorted)
#define NTILES    ((NEDGE + TILE - 1) / TILE)
#define SPLIT     8                       // blocks per bucket in the hop

typedef unsigned int uint4v __attribute__((ext_vector_type(4)));
typedef int          int4v  __attribute__((ext_vector_type(4)));
typedef float        flt4v  __attribute__((ext_vector_type(4)));

// ---------------- binned path ----------------

__global__ void init_cursors(unsigned* __restrict__ cursors) {
    int i = blockIdx.x * blockDim.x + threadIdx.x;
    if (i < NB) cursors[i] = (unsigned)i * CAP;
}

// Tile-sorted scatter: counting-sort a 4096-edge tile by dst bucket in LDS,
// reserve one contiguous global range per (tile,bucket), flush coalesced runs.
// All input loads are int4/float4 nt vectors issued up-front: 192B/lane in
// flight (~12KB/wave) to approach HBM BW (rounds 9/11 realized only 1.2-1.5
// TB/s with scalar loads -> latency-bound streaming was the scatter bound).
__global__ __launch_bounds__(256) void scatter_bin(
    const int* __restrict__ src, const int* __restrict__ dst,
    const float* __restrict__ ew, uint2* __restrict__ rec,
    unsigned* __restrict__ cursors) {
    __shared__ uint2 srec[TILE];             // 32KB tile records, bucket-sorted
    __shared__ unsigned short sbkt[TILE];    // 8KB bucket id per sorted pos
    __shared__ unsigned hist[NB];
    __shared__ unsigned curs[NB];
    __shared__ unsigned gpos[NB];
    int tid = threadIdx.x;

    for (int tile = blockIdx.x; tile < NTILES; tile += gridDim.x) {
        int e0 = tile * TILE;
        int n_this = (e0 + TILE <= NEDGE) ? TILE : (NEDGE - e0);  // mult of 4
        int nq = n_this >> 2;                                     // int4 count
        int q0 = e0 >> 2;

        for (int i = tid; i < NB; i += 256) hist[i] = 0;
        __syncthreads();

        int4v dv[4]; int4v sv[4]; flt4v wv[4];
        #pragma unroll
        for (int k = 0; k < 4; ++k) {
            int q = k * 256 + tid;
            if (q < nq) {
                dv[k] = __builtin_nontemporal_load(reinterpret_cast<const int4v*>(dst) + q0 + q);
                sv[k] = __builtin_nontemporal_load(reinterpret_cast<const int4v*>(src) + q0 + q);
                wv[k] = __builtin_nontemporal_load(reinterpret_cast<const flt4v*>(ew) + q0 + q);
            }
        }
        #pragma unroll
        for (int k = 0; k < 4; ++k) {
            int q = k * 256 + tid;
            if (q < nq) {
                #pragma unroll
                for (int j = 0; j < 4; ++j)
                    atomicAdd(&hist[dv[k][j] >> SBITS], 1u);
            }
        }
        __syncthreads();

        if (tid == 0) {                       // exclusive scan over 245 buckets
            unsigned run = 0;
            for (int b = 0; b < NB; ++b) { unsigned v = hist[b]; hist[b] = run; run += v; }
        }
        __syncthreads();

        for (int b = tid; b < NB; b += 256) {
            unsigned st = hist[b];
            unsigned en = (b == NB - 1) ? (unsigned)n_this : hist[b + 1];
            unsigned c = en - st;
            gpos[b] = c ? atomicAdd(&cursors[b], c) : 0u;
            curs[b] = 0;
        }
        __syncthreads();

        #pragma unroll
        for (int k = 0; k < 4; ++k) {
            int q = k * 256 + tid;
            if (q < nq) {
                #pragma unroll
                for (int j = 0; j < 4; ++j) {
                    int dd = dv[k][j], ss = sv[k][j];
                    int b = dd >> SBITS;
                    unsigned p = hist[b] + atomicAdd(&curs[b], 1u);
                    srec[p] = make_uint2(((unsigned)(dd & (S_BUCKET - 1)) << 20) | (unsigned)ss,
                                         __float_as_uint(wv[k][j]));
                    sbkt[p] = (unsigned short)b;
                }
            }
        }
        __syncthreads();

        for (int i = tid; i < n_this; i += 256) {   // coalesced segment flush
            unsigned b = sbkt[i];
            rec[gpos[b] + ((unsigned)i - hist[b])] = srec[i];
        }
        __syncthreads();                            // before next tile reuses LDS
    }
}

// LDS-accumulation hop: SPLIT blocks per 4096-node bucket; stream the bucket's
// records (nt), gather cur[src], ds_add_f32 into 16KB accumulator (fire-and-
// forget), coalesced global atomicAdd flush (nxt pre-zeroed). 8 records/iter
// (4x uint4 nt loads) keep 8 independent gathers in flight per lane.
__global__ __launch_bounds__(256) void hop_bucket(
    const uint2* __restrict__ rec, const unsigned* __restrict__ cursors,
    const float* __restrict__ cur, float* __restrict__ nxt) {
    __shared__ float acc[S_BUCKET];
    int tid = threadIdx.x;
    int b = blockIdx.x / SPLIT;
    int sidx = blockIdx.x % SPLIT;
    for (int i = tid; i < S_BUCKET; i += 256) acc[i] = 0.0f;
    __syncthreads();

    unsigned start = (unsigned)b * CAP;          // CAP mult of 8 -> 64B aligned
    unsigned cnt = cursors[b] - start;
    unsigned u0 = ((cnt * (unsigned)sidx) / SPLIT) & ~7u;
    unsigned u1 = (sidx == SPLIT - 1) ? cnt : (((cnt * (unsigned)(sidx + 1)) / SPLIT) & ~7u);
    const uint2* bp = rec + start;

    unsigned i = u0 + 8u * (unsigned)tid;
    for (; i + 8u <= u1; i += 8u * 256u) {
        uint4v r0 = __builtin_nontemporal_load(reinterpret_cast<const uint4v*>(bp + i));
        uint4v r1 = __builtin_nontemporal_load(reinterpret_cast<const uint4v*>(bp + i + 2));
        uint4v r2 = __builtin_nontemporal_load(reinterpret_cast<const uint4v*>(bp + i + 4));
        uint4v r3 = __builtin_nontemporal_load(reinterpret_cast<const uint4v*>(bp + i + 6));
        float c0 = cur[r0.x & 0xFFFFFu];
        float c1 = cur[r0.z & 0xFFFFFu];
        float c2 = cur[r1.x & 0xFFFFFu];
        float c3 = cur[r1.z & 0xFFFFFu];
        float c4 = cur[r2.x & 0xFFFFFu];
        float c5 = cur[r2.z & 0xFFFFFu];
        float c6 = cur[r3.x & 0xFFFFFu];
        float c7 = cur[r3.z & 0xFFFFFu];
        atomicAdd(&acc[r0.x >> 20], c0 * __uint_as_float(r0.y));
        atomicAdd(&acc[r0.z >> 20], c1 * __uint_as_float(r0.w));
        atomicAdd(&acc[r1.x >> 20], c2 * __uint_as_float(r1.y));
        atomicAdd(&acc[r1.z >> 20], c3 * __uint_as_float(r1.w));
        atomicAdd(&acc[r2.x >> 20], c4 * __uint_as_float(r2.y));
        atomicAdd(&acc[r2.z >> 20], c5 * __uint_as_float(r2.w));
        atomicAdd(&acc[r3.x >> 20], c6 * __uint_as_float(r3.y));
        atomicAdd(&acc[r3.z >> 20], c7 * __uint_as_float(r3.w));
    }
    if (i < u1) {                                // straddling remainder (<8), one thread
        for (unsigned j = i; j < i + 8u && j < u1; ++j) {
            uint2 r = bp[j];
            atomicAdd(&acc[r.x >> 20], cur[r.x & 0xFFFFFu] * __uint_as_float(r.y));
        }
    }
    __syncthreads();

    int nb0 = b << SBITS;
    for (int k = tid; k < S_BUCKET; k += 256) {
        int n = nb0 + k;
        if (n < N_USERS) atomicAdd(&nxt[n], acc[k]);
    }
}

// ---------------- fallback path (device atomics, small workspace) ----------------

__global__ void zero_kernel(float* __restrict__ p, int n) {
    int i = blockIdx.x * blockDim.x + threadIdx.x;
    int stride = gridDim.x * blockDim.x;
    for (; i < n; i += stride) p[i] = 0.0f;
}

__global__ __launch_bounds__(256) void hop_atomic(
    const int* __restrict__ src, const int* __restrict__ dst,
    const float* __restrict__ ew, const float* __restrict__ cur,
    float* __restrict__ nxt) {
    int e = blockIdx.x * blockDim.x + threadIdx.x;
    if (e * 4 < NEDGE) {
        int4   s = ((const int4*)src)[e];
        int4   d = ((const int4*)dst)[e];
        float4 w = ((const float4*)ew)[e];
        atomicAdd(&nxt[d.x], cur[s.x] * w.x);
        atomicAdd(&nxt[d.y], cur[s.y] * w.y);
        atomicAdd(&nxt[d.z], cur[s.z] * w.z);
        atomicAdd(&nxt[d.w], cur[s.w] * w.w);
    }
}

// ---------------- finalize: 5->64 matvec + BatchNorm over features ----------------

__global__ __launch_bounds__(256) void finalize_kernel(
    const float* __restrict__ x,  const float* __restrict__ f1,
    const float* __restrict__ f2, const float* __restrict__ f3,
    const float* __restrict__ f4, const float* __restrict__ W,
    const float* __restrict__ bias, const float* __restrict__ gamma,
    const float* __restrict__ beta, float* __restrict__ out) {
    int lane = threadIdx.x & 63;
    int waveInBlock = threadIdx.x >> 6;
    int wavesPerBlock = blockDim.x >> 6;
    int gwave  = blockIdx.x * wavesPerBlock + waveInBlock;
    int nwaves = gridDim.x * wavesPerBlock;

    float w0 = W[lane * 5 + 0];
    float w1 = W[lane * 5 + 1];
    float w2 = W[lane * 5 + 2];
    float w3 = W[lane * 5 + 3];
    float w4 = W[lane * 5 + 4];
    float b  = bias[lane];

    for (int n = gwave; n < N_USERS; n += nwaves) {
        float c0 = x[n], c1 = f1[n], c2 = f2[n], c3 = f3[n], c4 = f4[n];
        float y = b + c0 * w0 + c1 * w1 + c2 * w2 + c3 * w3 + c4 * w4;

        float s = y;
        #pragma unroll
        for (int off = 32; off; off >>= 1) s += __shfl_xor(s, off);
        float mean = s * (1.0f / 64.0f);

        float d = y - mean;
        float v = d * d;
        #pragma unroll
        for (int off = 32; off; off >>= 1) v += __shfl_xor(v, off);
        float var = v * (1.0f / 64.0f);

        float o = d * rsqrtf(var + BN_EPS) * gamma[n] + beta[n];
        __builtin_nontemporal_store(o, &out[(size_t)n * OUT_F + lane]);
    }
}

extern "C" void kernel_launch(void* const* d_in, const int* in_sizes, int n_in,
                              void* d_out, int out_size, void* d_ws, size_t ws_size,
                              hipStream_t stream) {
    const float* x     = (const float*)d_in[0];
    const int*   ei    = (const int*)d_in[1];
    const float* ew    = (const float*)d_in[2];
    const float* W     = (const float*)d_in[3];
    const float* bias  = (const float*)d_in[4];
    const float* gamma = (const float*)d_in[5];
    const float* beta  = (const float*)d_in[6];
    float* out = (float*)d_out;

    const int* src = ei;
    const int* dst = ei + NEDGE;

    // Workspace layout (total ~284.3MB; known-available >= 304MB from rounds 0-1)
    float* f = (float*)d_ws;                                   // 16MB
    uint2* rec = (uint2*)(f + 4ull * N_USERS);                 // 268.3MB (padded)
    unsigned* cursors = (unsigned*)(rec + (size_t)NB * CAP);   // 4KB
    size_t needed = 16000000ull + (size_t)NB * CAP * 8 + 4096;

    if (ws_size >= needed) {
        init_cursors<<<1, 256, 0, stream>>>(cursors);
        zero_kernel<<<2048, 256, 0, stream>>>(f, 4 * N_USERS);   // hop flush is atomicAdd
        scatter_bin<<<SCAT_BLOCKS, 256, 0, stream>>>(src, dst, ew, rec, cursors);
        const float* cur = x;
        for (int h = 0; h < 4; ++h) {
            float* nxt = f + (size_t)h * N_USERS;
            hop_bucket<<<NB * SPLIT, 256, 0, stream>>>(rec, cursors, cur, nxt);
            cur = nxt;
        }
    } else {
        zero_kernel<<<4096, 256, 0, stream>>>(f, 4 * N_USERS);
        const float* cur = x;
        for (int h = 0; h < 4; ++h) {
            float* nxt = f + (size_t)h * N_USERS;
            hop_atomic<<<NEDGE / 4 / 256, 256, 0, stream>>>(src, dst, ew, cur, nxt);
            cur = nxt;
        }
    }

    finalize_kernel<<<2048, 256, 0, stream>>>(
        x, f, f + N_USERS, f + 2 * N_USERS, f + 3 * N_USERS,
        W, bias, gamma, beta, out);
}